// Round 22
// baseline (114.922 us; speedup 1.0000x reference)
//
#include <hip/hip_runtime.h>
#include <math.h>

typedef _Float16 f16;
typedef _Float16 f16x2 __attribute__((ext_vector_type(2)));
typedef _Float16 f16x4 __attribute__((ext_vector_type(4)));
typedef _Float16 f16x8 __attribute__((ext_vector_type(8)));
typedef float    f32x4 __attribute__((ext_vector_type(4)));

constexpr int DIM   = 1024;
constexpr int HEADS = 16;
constexpr int HD    = 64;
constexpr int BATCH = 2;
constexpr int SEQ   = 2048;
constexpr int MTOT  = BATCH * SEQ;   // 4096
constexpr int NT2   = SEQ / 128;     // 16 staged KV tiles of 128

// exp(q.k/64) == exp2((q * log2e/64) . k): fold into Q projection scale.
#define QSCALE (1.4426950408889634f / 64.0f)

#define MFMA16(a, b, c) __builtin_amdgcn_mfma_f32_16x16x32_f16((a), (b), (c), 0, 0, 0)

__device__ __forceinline__ void glds16(const void* g, void* l) {
    __builtin_amdgcn_global_load_lds(
        (const __attribute__((address_space(1))) void*)g,
        (__attribute__((address_space(3))) void*)l, 16, 0, 0);
}

__device__ __forceinline__ float exp2_hw(float x) {
    float r;
    asm("v_exp_f32 %0, %1" : "=v"(r) : "v"(x));   // D = 2^S0
    return r;
}

__device__ __forceinline__ f16x2 pk_f16(float a, float b) {
    return __builtin_bit_cast(f16x2, __builtin_amdgcn_cvt_pkrtz(a, b));
}

// ---------------------------------------------------------------------------
// Pre-split pass: fp32 -> f16 hi planes, GEMM fragment-read swizzle baked:
// within each 32-half k-tile, 8-half slot ^= ((row>>1)&3).
// ---------------------------------------------------------------------------
__global__ __launch_bounds__(256) void presplit_kernel(
    const float* __restrict__ x,  const float* __restrict__ Wq,
    const float* __restrict__ Wk, const float* __restrict__ Wv,
    const float* __restrict__ Wo,
    f16* __restrict__ Xh,  f16* __restrict__ WqH, f16* __restrict__ WkH,
    f16* __restrict__ WvH, f16* __restrict__ WoH)
{
    const int bid = blockIdx.x;
    const float* src; f16* dh; int row;
    if (bid < 4096)      { src = x;  dh = Xh;  row = bid; }
    else if (bid < 5120) { src = Wq; dh = WqH; row = bid - 4096; }
    else if (bid < 6144) { src = Wk; dh = WkH; row = bid - 5120; }
    else if (bid < 7168) { src = Wv; dh = WvH; row = bid - 6144; }
    else                 { src = Wo; dh = WoH; row = bid - 7168; }

    const int k = threadIdx.x * 4;
    const float4 v = *reinterpret_cast<const float4*>(&src[(size_t)row * DIM + k]);
    const int s = (row >> 1) & 3;
    const size_t o = (size_t)row * DIM + (k & ~31) + ((k & 31) ^ (s << 3));
    f16x4 h4;
    h4[0] = (f16)v.x; h4[1] = (f16)v.y; h4[2] = (f16)v.z; h4[3] = (f16)v.w;
    *reinterpret_cast<f16x4*>(&dh[o]) = h4;
}

// ---------------------------------------------------------------------------
// FUSED QKV v2.1: BM=128 x BN=64 (one head/block), 512 blocks = 2/CU,
// 3-buffer ring (3 x 20 KB), 2-deep prefetch, counted vmcnt (R20 proven).
// Q epilogue via padded LDS repack -> f16x8 coalesced stores.
// ---------------------------------------------------------------------------
__global__ __launch_bounds__(256, 2) void qkv_kernel(
    const f16* __restrict__ XhG,
    const f16* __restrict__ WqH, const float* __restrict__ bq,
    const f16* __restrict__ WkH, const float* __restrict__ bk,
    const f16* __restrict__ WvH, const float* __restrict__ bv,
    f16* __restrict__ QhG, f16* __restrict__ KhG, f16* __restrict__ VhG)
{
    __shared__ __align__(16) f16 smem[30720];   // 60 KB: 3 x 10240-half ring

    const int tid = threadIdx.x;
    const int l   = tid & 63;
    const int w   = tid >> 6;
    const int wm  = (w >> 1) * 64;      // token offset
    const int wn  = (w & 1) * 32;       // col offset within head
    const int m0  = blockIdx.y * 128;
    const int n0  = blockIdx.x * 64;    // one head
    const int fr  = l & 15;
    const int fk  = (l >> 4) * 8;
    const int rg  = (l >> 4) * 4;
    const int fko = fk ^ (((fr >> 1) & 3) << 3);

    f32x4 accq[4][2] = {}, acck[4][2] = {}, accv[4][2] = {};

    // 20 chunks of 512 halves: 0-7 x (16 rows ea), 8-19 W planes (4 ea).
#define GSTAGE(B, K0) do {                                                  \
        _Pragma("unroll")                                                   \
        for (int j = 0; j < 5; ++j) {                                       \
            const int c = w * 5 + j;                                        \
            const f16* P; int row, dst;                                     \
            if (c < 8) {                                                    \
                P = XhG; row = m0 + c * 16 + (l >> 2); dst = c * 512;       \
            } else {                                                        \
                const int p  = (c - 8) >> 2;                                \
                const int cc = (c - 8) & 3;                                 \
                P = (p == 0) ? WqH : (p == 1) ? WkH : WvH;                  \
                row = n0 + cc * 16 + (l >> 2);                              \
                dst = 4096 + p * 2048 + cc * 512;                           \
            }                                                               \
            glds16(P + (size_t)row * DIM + (K0) + (l & 3) * 8,              \
                   smem + (B) * 10240 + dst);                               \
        }                                                                   \
    } while (0)

    GSTAGE(0, 0);
    GSTAGE(1, 32);
    int b0 = 0, b1 = 1, b2 = 2;

    for (int k0 = 0; k0 < DIM; k0 += 32) {
        if (k0 + 64 < DIM) {
            GSTAGE(b2, k0 + 64);
            asm volatile("s_waitcnt vmcnt(10)\ns_barrier" ::: "memory");
        } else if (k0 + 32 < DIM) {
            asm volatile("s_waitcnt vmcnt(5)\ns_barrier" ::: "memory");
        } else {
            asm volatile("s_waitcnt vmcnt(0)\ns_barrier" ::: "memory");
        }

        const f16* Bu = smem + b0 * 10240;
        f16x8 ah[4], bqf[2], bkf[2], bvf[2];
        #pragma unroll
        for (int m = 0; m < 4; ++m)
            ah[m] = *reinterpret_cast<const f16x8*>(&Bu[(wm + m * 16 + fr) * 32 + fko]);
        #pragma unroll
        for (int n = 0; n < 2; ++n) {
            const int r = (wn + n * 16 + fr) * 32 + fko;
            bqf[n] = *reinterpret_cast<const f16x8*>(&Bu[4096 + r]);
            bkf[n] = *reinterpret_cast<const f16x8*>(&Bu[6144 + r]);
            bvf[n] = *reinterpret_cast<const f16x8*>(&Bu[8192 + r]);
        }
        #pragma unroll
        for (int n = 0; n < 2; ++n)
            #pragma unroll
            for (int m = 0; m < 4; ++m) {
                accq[m][n] = MFMA16(ah[m], bqf[n], accq[m][n]);
                acck[m][n] = MFMA16(bkf[n], ah[m], acck[m][n]);   // D[d][token]
                accv[m][n] = MFMA16(ah[m], bvf[n], accv[m][n]);
            }
        asm volatile("s_barrier" ::: "memory");
        const int tmp = b0; b0 = b1; b1 = b2; b2 = tmp;
    }
#undef GSTAGE

    const int batch = m0 >> 11;
    const int kvg0  = m0 & 2047;
    const size_t bh_ = (size_t)batch * HEADS + (n0 >> 6);

    // ---- Q epilogue: LDS repack [128][72] -> coalesced f16x8 stores ----
    {
        constexpr int QRS = 72;
        #pragma unroll
        for (int n = 0; n < 2; ++n) {
            const int col  = wn + n * 16 + fr;
            const float bb = bq[n0 + col];
            #pragma unroll
            for (int m = 0; m < 4; ++m)
                #pragma unroll
                for (int r = 0; r < 4; ++r) {
                    const int rowl = wm + m * 16 + rg + r;
                    smem[rowl * QRS + col] = (f16)((accq[m][n][r] + bb) * QSCALE);
                }
        }
        __syncthreads();
        const int row = tid >> 1, c0 = (tid & 1) * 32;
        #pragma unroll
        for (int j = 0; j < 4; ++j) {
            *reinterpret_cast<f16x8*>(
                &QhG[(size_t)(m0 + row) * DIM + n0 + c0 + j * 8]) =
                *reinterpret_cast<const f16x8*>(&smem[row * QRS + c0 + j * 8]);
        }
        __syncthreads();
    }

    // ---- K epilogue: [bh][kv][ d ^ ((kv&7)<<3) ] via LDS repack ----
    {
        constexpr int RS = 72;
        #pragma unroll
        for (int n = 0; n < 2; ++n) {
            #pragma unroll
            for (int m = 0; m < 4; ++m) {
                const int kvrow = wm + m * 16 + fr;
                const int dd    = wn + n * 16 + rg;
                f16x4 h4;
                #pragma unroll
                for (int r = 0; r < 4; ++r)
                    h4[r] = (f16)(acck[m][n][r] + bk[n0 + dd + r]);
                const int o = kvrow * RS + (dd ^ ((kvrow & 7) << 3));
                *reinterpret_cast<f16x4*>(&smem[o]) = h4;
            }
        }
        __syncthreads();
        const int row = tid >> 1, c0 = (tid & 1) * 32;
        #pragma unroll
        for (int j = 0; j < 4; ++j) {
            const int so = row * RS + c0 + j * 8;
            const size_t go = bh_ * 131072 + (size_t)(kvg0 + row) * 64 + c0 + j * 8;
            *reinterpret_cast<f16x8*>(&KhG[go]) =
                *reinterpret_cast<const f16x8*>(&smem[so]);
        }
        __syncthreads();
    }

    // ---- V epilogue: [bh][d][ kv ^ ((d&7)<<3) ] via LDS repack ----
    {
        constexpr int RS = 136;
        #pragma unroll
        for (int n = 0; n < 2; ++n) {
            const int d    = wn + n * 16 + fr;
            const float bb = bv[n0 + d];
            #pragma unroll
            for (int m = 0; m < 4; ++m) {
                const int kvl = wm + m * 16 + rg;
                f16x4 h4;
                h4[0] = (f16)(accv[m][n][0] + bb);
                h4[1] = (f16)(accv[m][n][1] + bb);
                h4[2] = (f16)(accv[m][n][2] + bb);
                h4[3] = (f16)(accv[m][n][3] + bb);
                const int o = d * RS + (kvl ^ ((d & 7) << 3));
                *reinterpret_cast<f16x4*>(&smem[o]) = h4;
            }
        }
        __syncthreads();
        const int row = tid >> 2, c0 = (tid & 3) * 32;
        #pragma unroll
        for (int j = 0; j < 4; ++j) {
            const int so = row * RS + c0 + j * 8;
            const size_t go = bh_ * 131072 + (size_t)row * 2048 + kvg0 + c0 + j * 8;
            *reinterpret_cast<f16x8*>(&VhG[go]) =
                *reinterpret_cast<const f16x8*>(&smem[so]);
        }
    }
}

// ---------------------------------------------------------------------------
// oproj v2.2: BM=128 x BN=64, 512 blocks = 2/CU, 3-buffer ring, 2-deep
// prefetch. fp32 output via LDS repack [128][68] -> float4 coalesced
// stores. FIX vs R21: copy-out covers all 128 rows (row = tid>>1, 8 float4
// per thread; R21's tid>>2 covered only rows 0..63 -> half-zero output).
// ---------------------------------------------------------------------------
__global__ __launch_bounds__(256, 2) void oproj_kernel(
    const f16* __restrict__ OhG, const f16* __restrict__ WoH,
    const float* __restrict__ bo, float* __restrict__ out)
{
    __shared__ __align__(16) f16 smem[18432];   // 36 KB: ring / f32 repack

    const int tid = threadIdx.x;
    const int l   = tid & 63;
    const int w   = tid >> 6;
    const int wm  = (w >> 1) * 64;
    const int wn  = (w & 1) * 32;
    const int m0  = blockIdx.y * 128;
    const int n0  = blockIdx.x * 64;
    const int fr  = l & 15;
    const int fk  = (l >> 4) * 8;
    const int rg  = (l >> 4) * 4;
    const int fko = fk ^ (((fr >> 1) & 3) << 3);

    f32x4 acc[4][2] = {};

    // 12 chunks: 0-7 A (16 rows ea), 8-11 B.
#define GSTAGE(B, K0) do {                                                  \
        _Pragma("unroll")                                                   \
        for (int j = 0; j < 3; ++j) {                                       \
            const int c = w * 3 + j;                                        \
            const f16* P; int row, dst;                                     \
            if (c < 8) { P = OhG; row = m0 + c * 16 + (l >> 2); dst = c * 512; } \
            else { P = WoH; row = n0 + (c - 8) * 16 + (l >> 2);             \
                   dst = 4096 + (c - 8) * 512; }                            \
            glds16(P + (size_t)row * DIM + (K0) + (l & 3) * 8,              \
                   smem + (B) * 6144 + dst);                                \
        }                                                                   \
    } while (0)

    GSTAGE(0, 0);
    GSTAGE(1, 32);
    int b0 = 0, b1 = 1, b2 = 2;

    for (int k0 = 0; k0 < DIM; k0 += 32) {
        if (k0 + 64 < DIM) {
            GSTAGE(b2, k0 + 64);
            asm volatile("s_waitcnt vmcnt(6)\ns_barrier" ::: "memory");
        } else if (k0 + 32 < DIM) {
            asm volatile("s_waitcnt vmcnt(3)\ns_barrier" ::: "memory");
        } else {
            asm volatile("s_waitcnt vmcnt(0)\ns_barrier" ::: "memory");
        }

        const f16* Ah = smem + b0 * 6144;
        const f16* Bh = Ah + 4096;

        f16x8 ah[4], bh[2];
        #pragma unroll
        for (int m = 0; m < 4; ++m)
            ah[m] = *reinterpret_cast<const f16x8*>(&Ah[(wm + m * 16 + fr) * 32 + fko]);
        #pragma unroll
        for (int n = 0; n < 2; ++n)
            bh[n] = *reinterpret_cast<const f16x8*>(&Bh[(wn + n * 16 + fr) * 32 + fko]);
        #pragma unroll
        for (int n = 0; n < 2; ++n)
            #pragma unroll
            for (int m = 0; m < 4; ++m)
                acc[m][n] = MFMA16(ah[m], bh[n], acc[m][n]);
        asm volatile("s_barrier" ::: "memory");
        const int tmp = b0; b0 = b1; b1 = b2; b2 = tmp;
    }
#undef GSTAGE

    // ---- epilogue: f32 LDS repack [128][68] -> float4 coalesced stores ----
    {
        float* fsm = reinterpret_cast<float*>(smem);   // 9216 floats avail
        constexpr int ORS = 68;                        // 128*68 = 8704 used
        #pragma unroll
        for (int n = 0; n < 2; ++n) {
            const int col  = wn + n * 16 + fr;
            const float bb = bo[n0 + col];
            #pragma unroll
            for (int m = 0; m < 4; ++m)
                #pragma unroll
                for (int r = 0; r < 4; ++r)
                    fsm[(wm + m * 16 + rg + r) * ORS + col] = acc[m][n][r] + bb;
        }
        __syncthreads();
        const int row = tid >> 1, c0 = (tid & 1) * 32;
        #pragma unroll
        for (int j = 0; j < 8; ++j) {
            *reinterpret_cast<float4*>(
                &out[(size_t)(m0 + row) * DIM + n0 + c0 + j * 4]) =
                *reinterpret_cast<const float4*>(&fsm[row * ORS + c0 + j * 4]);
        }
    }
}

// ---------------------------------------------------------------------------
// Flash attention (FROZEN at ~48.5 us / 4.88e-4): KVBLK=128 staging with
// counted-vmcnt dbuf, 4 waves, QBLK=32/wave, 512 blocks, 80 KB LDS,
// pure-f16 MFMA, exp2-folded scores, lsum via ones-MFMA, XCD swizzle.
// ---------------------------------------------------------------------------
__global__ __launch_bounds__(256, 2) void attn_kernel(
    const f16* __restrict__ QhG, const f16* __restrict__ KhG,
    const f16* __restrict__ VhG, f16* __restrict__ OhG)
{
    __shared__ __align__(16) f16 lds[2][2][8192];   // K: [128][64]; V: [2][64][64]
    __shared__ __align__(16) f16 PL[4][2][1024];    // 16 KB per-wave P^T

    const int tid = threadIdx.x;
    const int l   = tid & 63;
    const int w   = tid >> 6;
    const int fr  = l & 15;
    const int g   = l >> 4;
    const int fk  = g * 8;
    const int rg  = g * 4;
    const int swz = (fr & 7) << 3;

    const int lin  = blockIdx.x + 16 * (blockIdx.y + 16 * blockIdx.z);
    const int sid  = (lin & 7) * 64 + (lin >> 3);
    const int qblk = sid & 15;
    const int head = (sid >> 4) & 15;
    const int batch = sid >> 8;

    const int q0 = qblk * 128;
    const size_t rowbase = (size_t)batch * SEQ;
    const int hcol = head * HD;
    const size_t bhbase = ((size_t)batch * HEADS + head) * (size_t)(SEQ * HD);

    size_t kA[4], vA[4];
    #pragma unroll
    for (int c = 0; c < 4; ++c) {
        const int h0 = (w * 4 + c) * 512 + l * 8;
        kA[c] = bhbase + (size_t)h0;                               // + t*8192
        vA[c] = bhbase + (size_t)((h0 >> 6) & 63) * 2048
              + (size_t)(h0 >> 12) * 64 + (h0 & 63);               // + t*128
    }

#define STAGE(B, T) do {                                                    \
        const size_t _ko = (size_t)(T) * 8192;                              \
        const size_t _vo = (size_t)(T) * 128;                               \
        _Pragma("unroll")                                                   \
        for (int c = 0; c < 4; ++c) {                                       \
            const int lo_ = (w * 4 + c) * 512;                              \
            glds16(KhG + kA[c] + _ko, &lds[B][0][lo_]);                     \
            glds16(VhG + vA[c] + _vo, &lds[B][1][lo_]);                     \
        }                                                                   \
    } while (0)

    STAGE(0, 0);

    f16x8 qh[2][2];
    #pragma unroll
    for (int qb = 0; qb < 2; ++qb) {
        const f16* qp = &QhG[(rowbase + q0 + w * 32 + qb * 16 + fr) * DIM + hcol];
        qh[qb][0] = *reinterpret_cast<const f16x8*>(&qp[fk]);
        qh[qb][1] = *reinterpret_cast<const f16x8*>(&qp[32 + fk]);
    }

    f16x8 onesv;
    #pragma unroll
    for (int i = 0; i < 8; ++i) onesv[i] = (f16)1.0f;

    f32x4 ls[2] = {};
    f32x4 oa[4][2] = {};

    int cur = 0;
    for (int t = 0; t < NT2; ++t) {
        if (t + 1 < NT2) {
            STAGE(cur ^ 1, t + 1);
            asm volatile("s_waitcnt vmcnt(8)\ns_barrier" ::: "memory");
        } else {
            asm volatile("s_waitcnt vmcnt(0)\ns_barrier" ::: "memory");
        }

        #pragma unroll
        for (int hh = 0; hh < 2; ++hh) {
            const f16* Kh = &lds[cur][0][hh * 4096];
            const f16* Vh = &lds[cur][1][hh * 4096];

            f32x4 sa[4][2] = {};
            __builtin_amdgcn_s_setprio(1);
            #pragma unroll
            for (int kvb = 0; kvb < 4; ++kvb) {
                #pragma unroll
                for (int ks = 0; ks < 2; ++ks) {
                    const int o = ((kvb * 16 + fr) * 64 + ks * 32 + fk) ^ swz;
                    const f16x8 kh = *reinterpret_cast<const f16x8*>(&Kh[o]);
                    sa[kvb][0] = MFMA16(kh, qh[0][ks], sa[kvb][0]);
                    sa[kvb][1] = MFMA16(kh, qh[1][ks], sa[kvb][1]);
                }
            }
            __builtin_amdgcn_s_setprio(0);

            f16x8 pf[2][2];
            #pragma unroll
            for (int qb = 0; qb < 2; ++qb) {
                f16* Wh = &PL[w][qb][0];
                #pragma unroll
                for (int kvb = 0; kvb < 4; ++kvb) {
                    const f16x2 p01 = pk_f16(exp2_hw(sa[kvb][qb][0]),
                                             exp2_hw(sa[kvb][qb][1]));
                    const f16x2 p23 = pk_f16(exp2_hw(sa[kvb][qb][2]),
                                             exp2_hw(sa[kvb][qb][3]));
                    f16x4 h4;
                    h4[0] = p01[0]; h4[1] = p01[1]; h4[2] = p23[0]; h4[3] = p23[1];
                    const int po = (fr * 64 + kvb * 16 + rg) ^ swz;
                    *reinterpret_cast<f16x4*>(&Wh[po]) = h4;
                }
                #pragma unroll
                for (int ks = 0; ks < 2; ++ks) {
                    const int ro = (fr * 64 + ks * 32 + fk) ^ swz;
                    pf[qb][ks] = *reinterpret_cast<const f16x8*>(&Wh[ro]);
                }
            }

            __builtin_amdgcn_s_setprio(1);
            #pragma unroll
            for (int qb = 0; qb < 2; ++qb)
                #pragma unroll
                for (int ks = 0; ks < 2; ++ks)
                    ls[qb] = MFMA16(onesv, pf[qb][ks], ls[qb]);
            #pragma unroll
            for (int db = 0; db < 4; ++db) {
                #pragma unroll
                for (int ks = 0; ks < 2; ++ks) {
                    const int vo = (db * 16 + fr) * 64 + ((ks * 32 + fk) ^ swz);
                    const f16x8 vh = *reinterpret_cast<const f16x8*>(&Vh[vo]);
                    oa[db][0] = MFMA16(vh, pf[0][ks], oa[db][0]);
                    oa[db][1] = MFMA16(vh, pf[1][ks], oa[db][1]);
                }
            }
            __builtin_amdgcn_s_setprio(0);
        }
        asm volatile("s_barrier" ::: "memory");
        cur ^= 1;
    }
#undef STAGE

    #pragma unroll
    for (int qb = 0; qb < 2; ++qb) {
        const float inv = 1.0f / ls[qb][0];
        const size_t row = rowbase + q0 + w * 32 + qb * 16 + fr;
        const int s = ((int)row >> 1) & 3;
        #pragma unroll
        for (int db = 0; db < 4; ++db) {
            f16x4 h4;
            #pragma unroll
            for (int j = 0; j < 4; ++j) h4[j] = (f16)(oa[db][qb][j] * inv);
            const int kg = hcol + db * 16 + rg;
            const size_t o = row * DIM + (kg & ~31) + ((kg & 31) ^ (s << 3));
            *reinterpret_cast<f16x4*>(&OhG[o]) = h4;
        }
    }
}

extern "C" void kernel_launch(void* const* d_in, const int* in_sizes, int n_in,
                              void* d_out, int out_size, void* d_ws, size_t ws_size,
                              hipStream_t stream)
{
    const float* x  = (const float*)d_in[0];
    const float* Wq = (const float*)d_in[1];
    const float* bq = (const float*)d_in[2];
    const float* Wk = (const float*)d_in[3];
    const float* bk = (const float*)d_in[4];
    const float* Wv = (const float*)d_in[5];
    const float* bv = (const float*)d_in[6];
    const float* Wo = (const float*)d_in[7];
    const float* bo = (const float*)d_in[8];
    float* out = (float*)d_out;

    const size_t PS = (size_t)MTOT * DIM;   // 4,194,304 elements
    f16* QhG = (f16*)d_ws;                  // 8 MB each
    f16* KhG = QhG + PS;
    f16* VhG = KhG + PS;
    f16* XhG = VhG + PS;                    // reused as Oh after qkv
    f16* WqH = XhG + PS;                    // 2 MB each below
    f16* WkH = WqH + (size_t)DIM * DIM;
    f16* WvH = WkH + (size_t)DIM * DIM;
    f16* WoH = WvH + (size_t)DIM * DIM;
    f16* OhG = XhG;                         // alias: x consumed before attn

    presplit_kernel<<<8192, 256, 0, stream>>>(x, Wq, Wk, Wv, Wo,
                                              XhG, WqH, WkH, WvH, WoH);

    dim3 gqkv(DIM / 64, MTOT / 128);
    qkv_kernel<<<gqkv, 256, 0, stream>>>(XhG, WqH, bq, WkH, bk, WvH, bv,
                                         QhG, KhG, VhG);

    dim3 gattn(SEQ / 128, HEADS, BATCH);
    attn_kernel<<<gattn, 256, 0, stream>>>(QhG, KhG, VhG, OhG);

    dim3 gout(DIM / 64, MTOT / 128);
    oproj_kernel<<<gout, 256, 0, stream>>>(OhG, WoH, bo, out);
}

// Round 23
// 109.251 us; speedup vs baseline: 1.0519x; 1.0519x over previous
//
#include <hip/hip_runtime.h>
#include <math.h>

typedef _Float16 f16;
typedef _Float16 f16x2 __attribute__((ext_vector_type(2)));
typedef _Float16 f16x4 __attribute__((ext_vector_type(4)));
typedef _Float16 f16x8 __attribute__((ext_vector_type(8)));
typedef float    f32x4 __attribute__((ext_vector_type(4)));

constexpr int DIM   = 1024;
constexpr int HEADS = 16;
constexpr int HD    = 64;
constexpr int BATCH = 2;
constexpr int SEQ   = 2048;
constexpr int MTOT  = BATCH * SEQ;   // 4096
constexpr int NT2   = SEQ / 128;     // 16 staged KV tiles of 128

// exp(q.k/64) == exp2((q * log2e/64) . k): fold into Q projection scale.
#define QSCALE (1.4426950408889634f / 64.0f)

#define MFMA16(a, b, c) __builtin_amdgcn_mfma_f32_16x16x32_f16((a), (b), (c), 0, 0, 0)

__device__ __forceinline__ void glds16(const void* g, void* l) {
    __builtin_amdgcn_global_load_lds(
        (const __attribute__((address_space(1))) void*)g,
        (__attribute__((address_space(3))) void*)l, 16, 0, 0);
}

__device__ __forceinline__ float exp2_hw(float x) {
    float r;
    asm("v_exp_f32 %0, %1" : "=v"(r) : "v"(x));   // D = 2^S0
    return r;
}

__device__ __forceinline__ f16x2 pk_f16(float a, float b) {
    return __builtin_bit_cast(f16x2, __builtin_amdgcn_cvt_pkrtz(a, b));
}

// ---------------------------------------------------------------------------
// Pre-split pass: fp32 -> f16 hi planes, GEMM fragment-read swizzle baked:
// within each 32-half k-tile, 8-half slot ^= ((row>>1)&3).
// ---------------------------------------------------------------------------
__global__ __launch_bounds__(256) void presplit_kernel(
    const float* __restrict__ x,  const float* __restrict__ Wq,
    const float* __restrict__ Wk, const float* __restrict__ Wv,
    const float* __restrict__ Wo,
    f16* __restrict__ Xh,  f16* __restrict__ WqH, f16* __restrict__ WkH,
    f16* __restrict__ WvH, f16* __restrict__ WoH)
{
    const int bid = blockIdx.x;
    const float* src; f16* dh; int row;
    if (bid < 4096)      { src = x;  dh = Xh;  row = bid; }
    else if (bid < 5120) { src = Wq; dh = WqH; row = bid - 4096; }
    else if (bid < 6144) { src = Wk; dh = WkH; row = bid - 5120; }
    else if (bid < 7168) { src = Wv; dh = WvH; row = bid - 6144; }
    else                 { src = Wo; dh = WoH; row = bid - 7168; }

    const int k = threadIdx.x * 4;
    const float4 v = *reinterpret_cast<const float4*>(&src[(size_t)row * DIM + k]);
    const int s = (row >> 1) & 3;
    const size_t o = (size_t)row * DIM + (k & ~31) + ((k & 31) ^ (s << 3));
    f16x4 h4;
    h4[0] = (f16)v.x; h4[1] = (f16)v.y; h4[2] = (f16)v.z; h4[3] = (f16)v.w;
    *reinterpret_cast<f16x4*>(&dh[o]) = h4;
}

// ---------------------------------------------------------------------------
// FUSED QKV v2 (R20 proven, 109.9 us total): BM=128 x BN=64 (one head per
// block), 512 blocks = 2/CU. x staged once per k-step; 3-buffer ring
// (3 x 20 KB), 2-deep prefetch, counted vmcnt. Scalar Q stores (L2
// write-combining absorbs them; R22's repack variant regressed).
// ---------------------------------------------------------------------------
__global__ __launch_bounds__(256, 2) void qkv_kernel(
    const f16* __restrict__ XhG,
    const f16* __restrict__ WqH, const float* __restrict__ bq,
    const f16* __restrict__ WkH, const float* __restrict__ bk,
    const f16* __restrict__ WvH, const float* __restrict__ bv,
    f16* __restrict__ QhG, f16* __restrict__ KhG, f16* __restrict__ VhG)
{
    __shared__ __align__(16) f16 smem[30720];   // 60 KB: 3 x 10240-half ring

    const int tid = threadIdx.x;
    const int l   = tid & 63;
    const int w   = tid >> 6;
    const int wm  = (w >> 1) * 64;      // token offset
    const int wn  = (w & 1) * 32;       // col offset within head
    const int m0  = blockIdx.y * 128;
    const int n0  = blockIdx.x * 64;    // one head
    const int fr  = l & 15;
    const int fk  = (l >> 4) * 8;
    const int rg  = (l >> 4) * 4;
    const int fko = fk ^ (((fr >> 1) & 3) << 3);

    f32x4 accq[4][2] = {}, acck[4][2] = {}, accv[4][2] = {};

    // 20 chunks of 512 halves: 0-7 x (16 rows ea), 8-19 W planes (4 ea).
#define GSTAGE(B, K0) do {                                                  \
        _Pragma("unroll")                                                   \
        for (int j = 0; j < 5; ++j) {                                       \
            const int c = w * 5 + j;                                        \
            const f16* P; int row, dst;                                     \
            if (c < 8) {                                                    \
                P = XhG; row = m0 + c * 16 + (l >> 2); dst = c * 512;       \
            } else {                                                        \
                const int p  = (c - 8) >> 2;                                \
                const int cc = (c - 8) & 3;                                 \
                P = (p == 0) ? WqH : (p == 1) ? WkH : WvH;                  \
                row = n0 + cc * 16 + (l >> 2);                              \
                dst = 4096 + p * 2048 + cc * 512;                           \
            }                                                               \
            glds16(P + (size_t)row * DIM + (K0) + (l & 3) * 8,              \
                   smem + (B) * 10240 + dst);                               \
        }                                                                   \
    } while (0)

    GSTAGE(0, 0);
    GSTAGE(1, 32);
    int b0 = 0, b1 = 1, b2 = 2;

    for (int k0 = 0; k0 < DIM; k0 += 32) {
        if (k0 + 64 < DIM) {
            GSTAGE(b2, k0 + 64);
            asm volatile("s_waitcnt vmcnt(10)\ns_barrier" ::: "memory");
        } else if (k0 + 32 < DIM) {
            asm volatile("s_waitcnt vmcnt(5)\ns_barrier" ::: "memory");
        } else {
            asm volatile("s_waitcnt vmcnt(0)\ns_barrier" ::: "memory");
        }

        const f16* Bu = smem + b0 * 10240;
        f16x8 ah[4], bqf[2], bkf[2], bvf[2];
        #pragma unroll
        for (int m = 0; m < 4; ++m)
            ah[m] = *reinterpret_cast<const f16x8*>(&Bu[(wm + m * 16 + fr) * 32 + fko]);
        #pragma unroll
        for (int n = 0; n < 2; ++n) {
            const int r = (wn + n * 16 + fr) * 32 + fko;
            bqf[n] = *reinterpret_cast<const f16x8*>(&Bu[4096 + r]);
            bkf[n] = *reinterpret_cast<const f16x8*>(&Bu[6144 + r]);
            bvf[n] = *reinterpret_cast<const f16x8*>(&Bu[8192 + r]);
        }
        #pragma unroll
        for (int n = 0; n < 2; ++n)
            #pragma unroll
            for (int m = 0; m < 4; ++m) {
                accq[m][n] = MFMA16(ah[m], bqf[n], accq[m][n]);
                acck[m][n] = MFMA16(bkf[n], ah[m], acck[m][n]);   // D[d][token]
                accv[m][n] = MFMA16(ah[m], bvf[n], accv[m][n]);
            }
        asm volatile("s_barrier" ::: "memory");
        const int tmp = b0; b0 = b1; b1 = b2; b2 = tmp;
    }
#undef GSTAGE

    // ---- Q epilogue: f16 plain [row][col], scale folded ----
    #pragma unroll
    for (int n = 0; n < 2; ++n) {
        const int col  = n0 + wn + n * 16 + fr;
        const float bb = bq[col];
        #pragma unroll
        for (int m = 0; m < 4; ++m)
            #pragma unroll
            for (int r = 0; r < 4; ++r) {
                const int row = m0 + wm + m * 16 + rg + r;
                QhG[(size_t)row * DIM + col] = (f16)((accq[m][n][r] + bb) * QSCALE);
            }
    }

    const int batch = m0 >> 11;
    const int kvg0  = m0 & 2047;
    const size_t bh_ = (size_t)batch * HEADS + (n0 >> 6);

    // ---- K epilogue: [bh][kv][ d ^ ((kv&7)<<3) ] via LDS repack ----
    {
        constexpr int RS = 72;
        #pragma unroll
        for (int n = 0; n < 2; ++n) {
            #pragma unroll
            for (int m = 0; m < 4; ++m) {
                const int kvrow = wm + m * 16 + fr;
                const int dd    = wn + n * 16 + rg;
                f16x4 h4;
                #pragma unroll
                for (int r = 0; r < 4; ++r)
                    h4[r] = (f16)(acck[m][n][r] + bk[n0 + dd + r]);
                const int o = kvrow * RS + (dd ^ ((kvrow & 7) << 3));
                *reinterpret_cast<f16x4*>(&smem[o]) = h4;
            }
        }
        __syncthreads();
        const int row = tid >> 1, c0 = (tid & 1) * 32;
        #pragma unroll
        for (int j = 0; j < 4; ++j) {
            const int so = row * RS + c0 + j * 8;
            const size_t go = bh_ * 131072 + (size_t)(kvg0 + row) * 64 + c0 + j * 8;
            *reinterpret_cast<f16x8*>(&KhG[go]) =
                *reinterpret_cast<const f16x8*>(&smem[so]);
        }
        __syncthreads();
    }

    // ---- V epilogue: [bh][d][ kv ^ ((d&7)<<3) ] via LDS repack ----
    {
        constexpr int RS = 136;
        #pragma unroll
        for (int n = 0; n < 2; ++n) {
            const int d    = wn + n * 16 + fr;
            const float bb = bv[n0 + d];
            #pragma unroll
            for (int m = 0; m < 4; ++m) {
                const int kvl = wm + m * 16 + rg;
                f16x4 h4;
                h4[0] = (f16)(accv[m][n][0] + bb);
                h4[1] = (f16)(accv[m][n][1] + bb);
                h4[2] = (f16)(accv[m][n][2] + bb);
                h4[3] = (f16)(accv[m][n][3] + bb);
                const int o = d * RS + (kvl ^ ((d & 7) << 3));
                *reinterpret_cast<f16x4*>(&smem[o]) = h4;
            }
        }
        __syncthreads();
        const int row = tid >> 2, c0 = (tid & 3) * 32;
        #pragma unroll
        for (int j = 0; j < 4; ++j) {
            const int so = row * RS + c0 + j * 8;
            const size_t go = bh_ * 131072 + (size_t)row * 2048 + kvg0 + c0 + j * 8;
            *reinterpret_cast<f16x8*>(&VhG[go]) =
                *reinterpret_cast<const f16x8*>(&smem[so]);
        }
    }
}

// ---------------------------------------------------------------------------
// oproj v2 (R20 proven): BM=128 x BN=64, 512 blocks = 2/CU. 3-buffer ring
// (3x12 KB), 2-deep prefetch, counted vmcnt. Scalar fp32 stores.
// ---------------------------------------------------------------------------
__global__ __launch_bounds__(256, 2) void oproj_kernel(
    const f16* __restrict__ OhG, const f16* __restrict__ WoH,
    const float* __restrict__ bo, float* __restrict__ out)
{
    __shared__ __align__(16) f16 smem[18432];   // 36 KB: 3 x 6144-half ring

    const int tid = threadIdx.x;
    const int l   = tid & 63;
    const int w   = tid >> 6;
    const int wm  = (w >> 1) * 64;
    const int wn  = (w & 1) * 32;
    const int m0  = blockIdx.y * 128;
    const int n0  = blockIdx.x * 64;
    const int fr  = l & 15;
    const int fk  = (l >> 4) * 8;
    const int rg  = (l >> 4) * 4;
    const int fko = fk ^ (((fr >> 1) & 3) << 3);

    f32x4 acc[4][2] = {};

    // 12 chunks: 0-7 A (16 rows ea), 8-11 B.
#define GSTAGE(B, K0) do {                                                  \
        _Pragma("unroll")                                                   \
        for (int j = 0; j < 3; ++j) {                                       \
            const int c = w * 3 + j;                                        \
            const f16* P; int row, dst;                                     \
            if (c < 8) { P = OhG; row = m0 + c * 16 + (l >> 2); dst = c * 512; } \
            else { P = WoH; row = n0 + (c - 8) * 16 + (l >> 2);             \
                   dst = 4096 + (c - 8) * 512; }                            \
            glds16(P + (size_t)row * DIM + (K0) + (l & 3) * 8,              \
                   smem + (B) * 6144 + dst);                                \
        }                                                                   \
    } while (0)

    GSTAGE(0, 0);
    GSTAGE(1, 32);
    int b0 = 0, b1 = 1, b2 = 2;

    for (int k0 = 0; k0 < DIM; k0 += 32) {
        if (k0 + 64 < DIM) {
            GSTAGE(b2, k0 + 64);
            asm volatile("s_waitcnt vmcnt(6)\ns_barrier" ::: "memory");
        } else if (k0 + 32 < DIM) {
            asm volatile("s_waitcnt vmcnt(3)\ns_barrier" ::: "memory");
        } else {
            asm volatile("s_waitcnt vmcnt(0)\ns_barrier" ::: "memory");
        }

        const f16* Ah = smem + b0 * 6144;
        const f16* Bh = Ah + 4096;

        f16x8 ah[4], bh[2];
        #pragma unroll
        for (int m = 0; m < 4; ++m)
            ah[m] = *reinterpret_cast<const f16x8*>(&Ah[(wm + m * 16 + fr) * 32 + fko]);
        #pragma unroll
        for (int n = 0; n < 2; ++n)
            bh[n] = *reinterpret_cast<const f16x8*>(&Bh[(wn + n * 16 + fr) * 32 + fko]);
        #pragma unroll
        for (int n = 0; n < 2; ++n)
            #pragma unroll
            for (int m = 0; m < 4; ++m)
                acc[m][n] = MFMA16(ah[m], bh[n], acc[m][n]);
        asm volatile("s_barrier" ::: "memory");
        const int tmp = b0; b0 = b1; b1 = b2; b2 = tmp;
    }
#undef GSTAGE

    #pragma unroll
    for (int n = 0; n < 2; ++n) {
        const int col  = n0 + wn + n * 16 + fr;
        const float bb = bo[col];
        #pragma unroll
        for (int m = 0; m < 4; ++m)
            #pragma unroll
            for (int r = 0; r < 4; ++r) {
                const int row = m0 + wm + m * 16 + rg + r;
                out[(size_t)row * DIM + col] = acc[m][n][r] + bb;
            }
    }
}

// ---------------------------------------------------------------------------
// Flash attention (FROZEN at ~48.5 us / 4.88e-4): KVBLK=128 staging with
// counted-vmcnt dbuf, 4 waves, QBLK=32/wave, 512 blocks, 80 KB LDS,
// pure-f16 MFMA, exp2-folded scores, lsum via ones-MFMA, XCD swizzle.
// ---------------------------------------------------------------------------
__global__ __launch_bounds__(256, 2) void attn_kernel(
    const f16* __restrict__ QhG, const f16* __restrict__ KhG,
    const f16* __restrict__ VhG, f16* __restrict__ OhG)
{
    __shared__ __align__(16) f16 lds[2][2][8192];   // K: [128][64]; V: [2][64][64]
    __shared__ __align__(16) f16 PL[4][2][1024];    // 16 KB per-wave P^T

    const int tid = threadIdx.x;
    const int l   = tid & 63;
    const int w   = tid >> 6;
    const int fr  = l & 15;
    const int g   = l >> 4;
    const int fk  = g * 8;
    const int rg  = g * 4;
    const int swz = (fr & 7) << 3;

    const int lin  = blockIdx.x + 16 * (blockIdx.y + 16 * blockIdx.z);
    const int sid  = (lin & 7) * 64 + (lin >> 3);
    const int qblk = sid & 15;
    const int head = (sid >> 4) & 15;
    const int batch = sid >> 8;

    const int q0 = qblk * 128;
    const size_t rowbase = (size_t)batch * SEQ;
    const int hcol = head * HD;
    const size_t bhbase = ((size_t)batch * HEADS + head) * (size_t)(SEQ * HD);

    size_t kA[4], vA[4];
    #pragma unroll
    for (int c = 0; c < 4; ++c) {
        const int h0 = (w * 4 + c) * 512 + l * 8;
        kA[c] = bhbase + (size_t)h0;                               // + t*8192
        vA[c] = bhbase + (size_t)((h0 >> 6) & 63) * 2048
              + (size_t)(h0 >> 12) * 64 + (h0 & 63);               // + t*128
    }

#define STAGE(B, T) do {                                                    \
        const size_t _ko = (size_t)(T) * 8192;                              \
        const size_t _vo = (size_t)(T) * 128;                               \
        _Pragma("unroll")                                                   \
        for (int c = 0; c < 4; ++c) {                                       \
            const int lo_ = (w * 4 + c) * 512;                              \
            glds16(KhG + kA[c] + _ko, &lds[B][0][lo_]);                     \
            glds16(VhG + vA[c] + _vo, &lds[B][1][lo_]);                     \
        }                                                                   \
    } while (0)

    STAGE(0, 0);

    f16x8 qh[2][2];
    #pragma unroll
    for (int qb = 0; qb < 2; ++qb) {
        const f16* qp = &QhG[(rowbase + q0 + w * 32 + qb * 16 + fr) * DIM + hcol];
        qh[qb][0] = *reinterpret_cast<const f16x8*>(&qp[fk]);
        qh[qb][1] = *reinterpret_cast<const f16x8*>(&qp[32 + fk]);
    }

    f16x8 onesv;
    #pragma unroll
    for (int i = 0; i < 8; ++i) onesv[i] = (f16)1.0f;

    f32x4 ls[2] = {};
    f32x4 oa[4][2] = {};

    int cur = 0;
    for (int t = 0; t < NT2; ++t) {
        if (t + 1 < NT2) {
            STAGE(cur ^ 1, t + 1);
            asm volatile("s_waitcnt vmcnt(8)\ns_barrier" ::: "memory");
        } else {
            asm volatile("s_waitcnt vmcnt(0)\ns_barrier" ::: "memory");
        }

        #pragma unroll
        for (int hh = 0; hh < 2; ++hh) {
            const f16* Kh = &lds[cur][0][hh * 4096];
            const f16* Vh = &lds[cur][1][hh * 4096];

            f32x4 sa[4][2] = {};
            __builtin_amdgcn_s_setprio(1);
            #pragma unroll
            for (int kvb = 0; kvb < 4; ++kvb) {
                #pragma unroll
                for (int ks = 0; ks < 2; ++ks) {
                    const int o = ((kvb * 16 + fr) * 64 + ks * 32 + fk) ^ swz;
                    const f16x8 kh = *reinterpret_cast<const f16x8*>(&Kh[o]);
                    sa[kvb][0] = MFMA16(kh, qh[0][ks], sa[kvb][0]);
                    sa[kvb][1] = MFMA16(kh, qh[1][ks], sa[kvb][1]);
                }
            }
            __builtin_amdgcn_s_setprio(0);

            f16x8 pf[2][2];
            #pragma unroll
            for (int qb = 0; qb < 2; ++qb) {
                f16* Wh = &PL[w][qb][0];
                #pragma unroll
                for (int kvb = 0; kvb < 4; ++kvb) {
                    const f16x2 p01 = pk_f16(exp2_hw(sa[kvb][qb][0]),
                                             exp2_hw(sa[kvb][qb][1]));
                    const f16x2 p23 = pk_f16(exp2_hw(sa[kvb][qb][2]),
                                             exp2_hw(sa[kvb][qb][3]));
                    f16x4 h4;
                    h4[0] = p01[0]; h4[1] = p01[1]; h4[2] = p23[0]; h4[3] = p23[1];
                    const int po = (fr * 64 + kvb * 16 + rg) ^ swz;
                    *reinterpret_cast<f16x4*>(&Wh[po]) = h4;
                }
                #pragma unroll
                for (int ks = 0; ks < 2; ++ks) {
                    const int ro = (fr * 64 + ks * 32 + fk) ^ swz;
                    pf[qb][ks] = *reinterpret_cast<const f16x8*>(&Wh[ro]);
                }
            }

            __builtin_amdgcn_s_setprio(1);
            #pragma unroll
            for (int qb = 0; qb < 2; ++qb)
                #pragma unroll
                for (int ks = 0; ks < 2; ++ks)
                    ls[qb] = MFMA16(onesv, pf[qb][ks], ls[qb]);
            #pragma unroll
            for (int db = 0; db < 4; ++db) {
                #pragma unroll
                for (int ks = 0; ks < 2; ++ks) {
                    const int vo = (db * 16 + fr) * 64 + ((ks * 32 + fk) ^ swz);
                    const f16x8 vh = *reinterpret_cast<const f16x8*>(&Vh[vo]);
                    oa[db][0] = MFMA16(vh, pf[0][ks], oa[db][0]);
                    oa[db][1] = MFMA16(vh, pf[1][ks], oa[db][1]);
                }
            }
            __builtin_amdgcn_s_setprio(0);
        }
        asm volatile("s_barrier" ::: "memory");
        cur ^= 1;
    }
#undef STAGE

    #pragma unroll
    for (int qb = 0; qb < 2; ++qb) {
        const float inv = 1.0f / ls[qb][0];
        const size_t row = rowbase + q0 + w * 32 + qb * 16 + fr;
        const int s = ((int)row >> 1) & 3;
        #pragma unroll
        for (int db = 0; db < 4; ++db) {
            f16x4 h4;
            #pragma unroll
            for (int j = 0; j < 4; ++j) h4[j] = (f16)(oa[db][qb][j] * inv);
            const int kg = hcol + db * 16 + rg;
            const size_t o = row * DIM + (kg & ~31) + ((kg & 31) ^ (s << 3));
            *reinterpret_cast<f16x4*>(&OhG[o]) = h4;
        }
    }
}

extern "C" void kernel_launch(void* const* d_in, const int* in_sizes, int n_in,
                              void* d_out, int out_size, void* d_ws, size_t ws_size,
                              hipStream_t stream)
{
    const float* x  = (const float*)d_in[0];
    const float* Wq = (const float*)d_in[1];
    const float* bq = (const float*)d_in[2];
    const float* Wk = (const float*)d_in[3];
    const float* bk = (const float*)d_in[4];
    const float* Wv = (const float*)d_in[5];
    const float* bv = (const float*)d_in[6];
    const float* Wo = (const float*)d_in[7];
    const float* bo = (const float*)d_in[8];
    float* out = (float*)d_out;

    const size_t PS = (size_t)MTOT * DIM;   // 4,194,304 elements
    f16* QhG = (f16*)d_ws;                  // 8 MB each
    f16* KhG = QhG + PS;
    f16* VhG = KhG + PS;
    f16* XhG = VhG + PS;                    // reused as Oh after qkv
    f16* WqH = XhG + PS;                    // 2 MB each below
    f16* WkH = WqH + (size_t)DIM * DIM;
    f16* WvH = WkH + (size_t)DIM * DIM;
    f16* WoH = WvH + (size_t)DIM * DIM;
    f16* OhG = XhG;                         // alias: x consumed before attn

    presplit_kernel<<<8192, 256, 0, stream>>>(x, Wq, Wk, Wv, Wo,
                                              XhG, WqH, WkH, WvH, WoH);

    dim3 gqkv(DIM / 64, MTOT / 128);
    qkv_kernel<<<gqkv, 256, 0, stream>>>(XhG, WqH, bq, WkH, bk, WvH, bv,
                                         QhG, KhG, VhG);

    dim3 gattn(SEQ / 128, HEADS, BATCH);
    attn_kernel<<<gattn, 256, 0, stream>>>(QhG, KhG, VhG, OhG);

    dim3 gout(DIM / 64, MTOT / 128);
    oproj_kernel<<<gout, 256, 0, stream>>>(OhG, WoH, bo, out);
}